// Round 8
// baseline (76.027 us; speedup 1.0000x reference)
//
#include <hip/hip_runtime.h>
#include <math.h>

// Problem constants (fixed shapes from setup_inputs)
#define B_    8
#define C_    4
#define H_    256
#define W_    256
#define NCLS  3                      // classes 1..3
#define NBLK  192                    // 3 cls x 8 b x 8 row-tiles(32 rows)
#define BIGVAL (1 << 26)             // pad value, never wins the min

// ---------------------------------------------------------------------------
// Fused kernel: vertical EDT (per-thread u64 bitmask over the full column,
// no cross-thread carries) + exact horizontal lower-envelope + loss partial.
//
// Block = (class, b, row-tile of 32). 256 threads; thread t owns column w=t
// for the vertical phase. Each block redundantly recomputes the vertical
// bitmasks for all 256 columns (mask is L2-resident; 8x redundancy is ~1 us
// aggregate) -- this removes ALL inter-block dependencies and the gbuf
// global round-trip.
//
// Vertical semantics (matches ref): d_up = h - (last bg row <= h), with
// last = -512 when none (=> d_up = h+512); d_down symmetric; g = min(du,dd,512).
// Exact: mask==cls bits excluded; BIG clamp = H+W = 512.
//
// Horizontal phase: 4 waves x 8 rows each, from the 64 KB LDS tile of g^2
// (padded 128 each side). Window exactness: D2[x] <= g2[x]; an x' improves
// only if |x-x'| <= g[x]-1 <= rowmax(g)-1 = R; all candidates are genuine
// upper bounds. Brute-force fallback for R >= 120 keeps worst-case exactness
// (window reads stay >= index 9, brute reads [128,384) -- so aliasing wsum
// onto ints 0..7 of row 0 is safe).
// ---------------------------------------------------------------------------
__global__ __launch_bounds__(256) void fused_kernel(const int* __restrict__ mask,
                                                    const float* __restrict__ pred,
                                                    double* __restrict__ acc) {
    __shared__ int lds[32 * 512];               // exactly 64 KB; row r at lds+512*r
    double* wsum = (double*)lds;                // aliases ints 0..7 of row 0 (safe, see above)

    const int t   = threadIdx.x;
    const int blk = blockIdx.x;
    const int c_i = blk >> 6;                   // 0..2
    const int b   = (blk >> 3) & 7;
    const int rt  = blk & 7;                    // row-tile: rows [rt*32, rt*32+32)
    const int cls = c_i + 1;

    // ---------------- Phase 1: vertical bitmask scan (thread = column t) ---
    const int* mcol = mask + (b << 16) + t;     // mask[b][h][t], row stride 256
    unsigned long long bg[4];
    #pragma unroll
    for (int k = 0; k < 4; ++k) {
        int mm[64];
        #pragma unroll
        for (int i = 0; i < 64; ++i) mm[i] = mcol[((k << 6) + i) << 8];
        unsigned long long v = 0ull;
        #pragma unroll
        for (int i = 0; i < 64; ++i) v |= (unsigned long long)(mm[i] != cls) << i;
        bg[k] = v;
    }
    int clast[4], cfirst[4];
    #pragma unroll
    for (int k = 0; k < 4; ++k) {
        clast[k]  = bg[k] ? ((k << 6) + 63 - __builtin_clzll(bg[k])) : -512;
        cfirst[k] = bg[k] ? ((k << 6) + __builtin_ctzll(bg[k])) : (1 << 20);
    }
    const int ci = rt >> 1;                     // chunk holding this 32-row tile
    int carry_up = -512;
    #pragma unroll
    for (int k = 0; k < 4; ++k) if (k < ci) carry_up = max(carry_up, clast[k]);
    int carry_dn = 1 << 20;
    #pragma unroll
    for (int k = 0; k < 4; ++k) if (k > ci) carry_dn = min(carry_dn, cfirst[k]);

    const unsigned long long bgc = bg[ci];
    const int i0 = (rt & 1) << 5;               // bit offset of tile within chunk
    #pragma unroll 4
    for (int r = 0; r < 32; ++r) {
        int ib = i0 + r;
        int h  = (ci << 6) + ib;
        unsigned long long le = bgc & (~0ull >> (63 - ib));   // bg at rows <= h
        int last  = le ? ((ci << 6) + 63 - __builtin_clzll(le)) : carry_up;
        int du = h - last;
        unsigned long long ge = bgc >> ib;                    // bg at rows >= h
        int first = ge ? (h + __builtin_ctzll(ge)) : carry_dn;
        int dd = first - h;
        int g = min(min(du, dd), 512);
        lds[r * 512 + 128 + t] = g * g;
    }
    // pads: indices [0,128) and [384,512) of every row
    const int pi = (t < 128) ? t : (256 + t);   // t<128 -> [0,128); else [384,512)
    #pragma unroll 4
    for (int r = 0; r < 32; ++r) lds[r * 512 + pi] = BIGVAL;
    __syncthreads();

    // ---------------- Phase 2: horizontal windowed envelope + loss ---------
    const int lane = t & 63;
    const int wv   = t >> 6;                    // wave handles rows wv*8..wv*8+7
    const int x0   = lane << 2;

    // prefetch this wave's 8 pred float4s (overlapped global latencies)
    const int pbase = (((b << 2) + cls) << 16) + (rt << 13) + (wv << 11) + x0;
    float4 pv[8];
    #pragma unroll
    for (int rr = 0; rr < 8; ++rr) pv[rr] = *(const float4*)(pred + pbase + (rr << 8));

    double sum = 0.0;
    #pragma unroll 1
    for (int rr = 0; rr < 8; ++rr) {
        const int* e = &lds[((wv << 3) + rr) * 512 + 128];
        int4 q = *(const int4*)&e[x0];
        int D2[4] = { q.x, q.y, q.z, q.w };

        int mq = max(max(q.x, q.y), max(q.z, q.w));
        #pragma unroll
        for (int off = 32; off > 0; off >>= 1) mq = max(mq, __shfl_xor(mq, off, 64));
        // exact integer sqrt of the (perfect-square) row max
        int gmax = (int)sqrtf((float)mq);
        gmax = (gmax * gmax > mq) ? gmax - 1 : gmax;
        gmax = ((gmax + 1) * (gmax + 1) <= mq) ? gmax + 1 : gmax;
        const int R = gmax - 1;

        if (R >= 120) {
            for (int xp = 0; xp < 256; ++xp) {
                int s = e[xp];
                #pragma unroll
                for (int j = 0; j < 4; ++j) {
                    int d = (x0 + j) - xp;
                    int cand = s + d * d;
                    D2[j] = (cand < D2[j]) ? cand : D2[j];
                }
            }
        } else if (R >= 1) {
            for (int o = 1; o <= R; ++o) {
                int oo = o * o;
                #pragma unroll
                for (int j = 0; j < 4; ++j) {
                    int xj = x0 + j;
                    int c1 = e[xj + o];
                    int c2 = e[xj - o];
                    int cm = (c1 < c2) ? c1 : c2;
                    int cand = cm + oo;
                    D2[j] = (cand < D2[j]) ? cand : D2[j];
                }
            }
        }

        sum += (double)(sqrtf((float)D2[0]) * pv[rr].x)
             + (double)(sqrtf((float)D2[1]) * pv[rr].y)
             + (double)(sqrtf((float)D2[2]) * pv[rr].z)
             + (double)(sqrtf((float)D2[3]) * pv[rr].w);
    }

    #pragma unroll
    for (int off = 32; off > 0; off >>= 1) sum += __shfl_xor(sum, off, 64);
    if (lane == 0) wsum[wv] = sum;              // ints 0..7 of row 0: never window-read
    __syncthreads();
    if (t == 0)
        acc[blk] = wsum[0] + wsum[1] + wsum[2] + wsum[3];
}

// ---------------------------------------------------------------------------
// Final: deterministic reduction of 192 block partials + normalization.
// ---------------------------------------------------------------------------
__global__ __launch_bounds__(64) void final_kernel(const double* __restrict__ acc,
                                                   float* __restrict__ out) {
    const int t = threadIdx.x;
    double s = acc[t] + acc[t + 64] + acc[t + 128];
    #pragma unroll
    for (int off = 32; off > 0; off >>= 1) s += __shfl_xor(s, off, 64);
    if (t == 0) {
        double nd = sqrt(131072.0) + 1e-6;          // sqrt(H^2+W^2)+1e-6
        double norm = (double)(float)nd;            // ref casts to float32
        out[0] = (float)(s / norm / ((double)NCLS * (double)(B_ * H_ * W_)));
    }
}

extern "C" void kernel_launch(void* const* d_in, const int* in_sizes, int n_in,
                              void* d_out, int out_size, void* d_ws, size_t ws_size,
                              hipStream_t stream) {
    const float* pred = (const float*)d_in[0];   // [8,4,256,256] f32
    const int*   mask = (const int*)d_in[1];     // [8,256,256] int
    float* out = (float*)d_out;

    double* acc = (double*)d_ws;                 // 192 doubles

    fused_kernel<<<NBLK, 256, 0, stream>>>(mask, pred, acc);
    final_kernel<<<1, 64, 0, stream>>>(acc, out);
}